// Round 1
// baseline (264.914 us; speedup 1.0000x reference)
//
#include <hip/hip_runtime.h>

// QattenNet: B=E*T=8192, S=256, A=32, O=128, QH1=128, QD=64, C1=128, H=4.
// Algebra: out[b] = sum_a q[b,a] * (f[b,a,:]·v[b,:]) + beta[b]*sumq[b] + c[b]
//   v[b,o]  = sum_k WkT[k,o] * emb[b,k],  WkT[k,o] = sum_h Wk[h,o,k]
//   emb     = relu(s@Wq1+bq1) @ Wq2 + bq2
//   beta[b] = emb[b,:]·bkSum,             bkSum[k] = sum_h bk[h,k]
//   c[b]    = relu(s@Wc1+bc1)·Wc2 + bc2

static constexpr int Sd  = 256;
static constexpr int Ad  = 32;
static constexpr int Od  = 128;
static constexpr int QH  = 128;
static constexpr int QDd = 64;
static constexpr int C1d = 128;
static constexpr int NB  = 16;   // b's per block

__global__ void qatten_prep(const float* __restrict__ Wk, const float* __restrict__ bk,
                            float* __restrict__ WkT, float* __restrict__ bkSum)
{
    int idx = blockIdx.x * 256 + threadIdx.x;   // 0..8191
    int k = idx >> 7;          // 0..63
    int o = idx & 127;         // 0..127
    float s = 0.f;
#pragma unroll
    for (int h = 0; h < 4; ++h) s += Wk[h * (Od * QDd) + o * QDd + k];
    WkT[k * Od + o] = s;
    if (idx < QDd) {
        float t = 0.f;
#pragma unroll
        for (int h = 0; h < 4; ++h) t += bk[h * QDd + idx];
        bkSum[idx] = t;
    }
}

__global__ __launch_bounds__(256) void qatten_main(
    const float* __restrict__ qv, const float* __restrict__ st, const float* __restrict__ fs,
    const float* __restrict__ Wq1, const float* __restrict__ bq1,
    const float* __restrict__ Wq2, const float* __restrict__ bq2,
    const float* __restrict__ Wc1, const float* __restrict__ bc1,
    const float* __restrict__ Wc2, const float* __restrict__ bc2,
    const float* __restrict__ WkT, const float* __restrict__ bkSum,
    float* __restrict__ out)
{
    __shared__ float s_lds[NB][Sd];     // 16 KB
    __shared__ float h1_lds[NB][QH];    // 8 KB
    __shared__ float hc_lds[NB][C1d];   // 8 KB
    __shared__ float emb_lds[NB][QDd];  // 4 KB
    __shared__ float v_lds[NB][Od];     // 8 KB
    __shared__ float q_lds[NB][Ad];     // 2 KB
    __shared__ float bias_lds[NB];
    __shared__ float part_lds[NB][256]; // 16 KB   total ~63.5 KB -> 2 blocks/CU

    const int tid = threadIdx.x;
    const int b0 = blockIdx.x * NB;

    // ---- stage s and q into LDS (coalesced float4) ----
    {
        const float4* sp = (const float4*)(st + (size_t)b0 * Sd);
        float4* sl = (float4*)&s_lds[0][0];
#pragma unroll
        for (int i = 0; i < (NB * Sd / 4) / 256; ++i)
            sl[tid + i * 256] = sp[tid + i * 256];
        const float* qp = qv + (size_t)b0 * Ad;
        float* ql = &q_lds[0][0];
#pragma unroll
        for (int i = 0; i < (NB * Ad) / 256; ++i)
            ql[tid + i * 256] = qp[tid + i * 256];
    }
    __syncthreads();

    // ---- phase 2: H1 = relu(s@Wq1+bq1) (waves 0-1), HC = relu(s@Wc1+bc1) (waves 2-3) ----
    {
        const int j = tid & 127;
        const bool isC = tid >= 128;
        const float* W  = isC ? Wc1 : Wq1;
        const float* bb = isC ? bc1 : bq1;
        float acc[NB];
#pragma unroll
        for (int b = 0; b < NB; ++b) acc[b] = 0.f;
        for (int i = 0; i < Sd; i += 4) {
            const float w0 = W[(i + 0) * 128 + j];   // coalesced across j
            const float w1 = W[(i + 1) * 128 + j];
            const float w2 = W[(i + 2) * 128 + j];
            const float w3 = W[(i + 3) * 128 + j];
#pragma unroll
            for (int b = 0; b < NB; ++b) {
                const float4 sv = *(const float4*)&s_lds[b][i];  // LDS broadcast
                float a = acc[b];
                a = fmaf(sv.x, w0, a);
                a = fmaf(sv.y, w1, a);
                a = fmaf(sv.z, w2, a);
                a = fmaf(sv.w, w3, a);
                acc[b] = a;
            }
        }
        const float bias = bb[j];
        float* dst = isC ? &hc_lds[0][0] : &h1_lds[0][0];
#pragma unroll
        for (int b = 0; b < NB; ++b)
            dst[b * 128 + j] = fmaxf(acc[b] + bias, 0.f);
    }
    __syncthreads();

    // ---- phase 3: emb = h1 @ Wq2 + bq2  (16x64 outputs, 4 per thread) ----
    {
        const int k = tid & 63;
        const int bg = tid >> 6;          // 0..3
        float acc[4] = {0.f, 0.f, 0.f, 0.f};
        for (int j = 0; j < QH; ++j) {
            const float w = Wq2[j * QDd + k];   // coalesced across k
#pragma unroll
            for (int r = 0; r < 4; ++r)
                acc[r] = fmaf(h1_lds[bg + 4 * r][j], w, acc[r]);
        }
        const float bias = bq2[k];
#pragma unroll
        for (int r = 0; r < 4; ++r)
            emb_lds[bg + 4 * r][k] = acc[r] + bias;
    }
    __syncthreads();

    // ---- phase 4: v[b,o] = sum_k emb[b,k] * WkT[k,o]  (16x128 outputs, 8 per thread) ----
    {
        const int o = tid & 127;
        const int bg = tid >> 7;          // 0..1
        float acc[8] = {0.f,0.f,0.f,0.f,0.f,0.f,0.f,0.f};
        for (int k = 0; k < QDd; ++k) {
            const float w = WkT[k * Od + o];    // coalesced across o
#pragma unroll
            for (int r = 0; r < 8; ++r)
                acc[r] = fmaf(emb_lds[bg + 2 * r][k], w, acc[r]);
        }
#pragma unroll
        for (int r = 0; r < 8; ++r)
            v_lds[bg + 2 * r][o] = acc[r];
    }
    __syncthreads();

    // ---- phase 5: bias[b] = c[b] + beta[b] * sumq[b]  (16 lanes per b) ----
    {
        const int b = tid >> 4;
        const int i = tid & 15;
        float pb = 0.f, pc = 0.f, pq = 0.f;
#pragma unroll
        for (int k = i; k < QDd; k += 16) pb = fmaf(emb_lds[b][k], bkSum[k], pb);
#pragma unroll
        for (int j = i; j < C1d; j += 16) pc = fmaf(hc_lds[b][j], Wc2[j], pc);
        pq = q_lds[b][i] + q_lds[b][i + 16];
#pragma unroll
        for (int d = 8; d >= 1; d >>= 1) {
            pb += __shfl_down(pb, d, 16);
            pc += __shfl_down(pc, d, 16);
            pq += __shfl_down(pq, d, 16);
        }
        if (i == 0) bias_lds[b] = (pc + bc2[0]) + pb * pq;
    }
    __syncthreads();

    // ---- phase 6: stream f, partial[tid] per b = sum_{a in mine} q[b,a]*(f4·v4) ----
    {
        const int oq = tid & 31;          // float4 index over o
        const int ag = tid >> 5;          // 0..7
#pragma unroll 4
        for (int b = 0; b < NB; ++b) {
            const float4* fb = (const float4*)(fs + ((size_t)(b0 + b)) * (Ad * Od));
            const float4 v4 = *(const float4*)&v_lds[b][oq * 4];
            float accb = 0.f;
#pragma unroll
            for (int r = 0; r < 4; ++r) {
                const int a = ag + 8 * r;
                const float4 f4 = fb[a * 32 + oq];    // coalesced 512B segments
                const float dot = f4.x * v4.x + f4.y * v4.y + f4.z * v4.z + f4.w * v4.w;
                accb = fmaf(q_lds[b][a], dot, accb);
            }
            part_lds[b][tid] = accb;
        }
    }
    __syncthreads();

    // ---- final reduction: out[b] = sum_t part[b][t] + bias[b] ----
    {
        const int b = tid >> 4;
        const int i = tid & 15;
        float sum = 0.f;
#pragma unroll
        for (int c = i; c < 256; c += 16) sum += part_lds[b][c];
#pragma unroll
        for (int d = 8; d >= 1; d >>= 1) sum += __shfl_down(sum, d, 16);
        if (i == 0) out[b0 + b] = sum + bias_lds[b];
    }
}

extern "C" void kernel_launch(void* const* d_in, const int* in_sizes, int n_in,
                              void* d_out, int out_size, void* d_ws, size_t ws_size,
                              hipStream_t stream) {
    const float* qv  = (const float*)d_in[0];
    const float* st  = (const float*)d_in[1];
    const float* fs  = (const float*)d_in[2];
    const float* Wq1 = (const float*)d_in[3];
    const float* bq1 = (const float*)d_in[4];
    const float* Wq2 = (const float*)d_in[5];
    const float* bq2 = (const float*)d_in[6];
    const float* Wk  = (const float*)d_in[7];
    const float* bk  = (const float*)d_in[8];
    const float* Wc1 = (const float*)d_in[9];
    const float* bc1 = (const float*)d_in[10];
    const float* Wc2 = (const float*)d_in[11];
    const float* bc2 = (const float*)d_in[12];
    float* out = (float*)d_out;

    float* WkT   = (float*)d_ws;            // 64*128 floats
    float* bkSum = WkT + QDd * Od;          // 64 floats

    qatten_prep<<<32, 256, 0, stream>>>(Wk, bk, WkT, bkSum);
    qatten_main<<<512, 256, 0, stream>>>(qv, st, fs, Wq1, bq1, Wq2, bq2,
                                         Wc1, bc1, Wc2, bc2, WkT, bkSum, out);
}